// Round 2
// baseline (357.829 us; speedup 1.0000x reference)
//
#include <hip/hip_runtime.h>

// FFF tree-routing MLP, MI355X — fp32 I/O (reference is fp32; round-1 NaN was
// bf16-misread of fp32 buffers).
// Shapes: B=4,S=2048 -> 8192 tokens; D_IN=D_OUT=2048; DEPTH=11 -> 4095 nodes.
//
//  K1: transpose w_out [2048,4095] -> w_out_T [4095,2048] in d_ws so the
//      per-token column gather becomes a contiguous 8KB row read.
//  K2: one wave (64 lanes) per token, 4 waves/block, no __syncthreads.
//      Per level: 8x float4 coalesced loads of w_in row, fp32 dot,
//      6-step shfl_xor butterfly (all lanes get the full score), exact-erf
//      GELU, fused acc += g * w_out_T[node] into 32 fp32 regs/lane,
//      sign picks the next node. float4 stores.
//  Fallback (ws too small): same kernel but strided column gather of w_out.

#define D_IN    2048
#define D_OUT   2048
#define DEPTHP1 12
#define N_NODES 4095
#define N_TOK   8192

// ---- K1: transpose w_out [D_OUT, N_NODES] -> w_out_T [N_NODES, D_OUT] ----
__global__ __launch_bounds__(1024) void transpose_wout(
    const float* __restrict__ in, float* __restrict__ out) {
    __shared__ float tile[32][33];
    const int n0 = blockIdx.x * 32;
    const int j0 = blockIdx.y * 32;
    const int tx = threadIdx.x, ty = threadIdx.y;
    const int n = n0 + tx;            // col in input (node), contiguous read
    const int j = j0 + ty;            // row in input (D_OUT index)
    if (n < N_NODES) tile[ty][tx] = in[(size_t)j * N_NODES + n];
    __syncthreads();
    const int nn = n0 + ty;           // row in output (node)
    const int jj = j0 + tx;           // col in output, contiguous write
    if (nn < N_NODES) out[(size_t)nn * D_OUT + jj] = tile[tx][ty];
}

// ---- K2: per-token traversal + fused output accumulation ----
template <bool TRANSPOSED>
__global__ __launch_bounds__(256) void fff_kernel(
    const float* __restrict__ x,       // [N_TOK, D_IN]
    const float* __restrict__ w_in,    // [N_NODES, D_IN]
    const float* __restrict__ w_out,   // TRANSPOSED ? [N_NODES,D_OUT] : [D_OUT,N_NODES]
    float* __restrict__ out) {         // [N_TOK, D_OUT]
    const int wave  = threadIdx.x >> 6;
    const int lane  = threadIdx.x & 63;
    const int token = blockIdx.x * 4 + wave;

    // Load this token's x row: 8 x float4 per lane = 32 fp32 regs.
    const float4* xrow = (const float4*)(x + (size_t)token * D_IN);
    float xf[32];
#pragma unroll
    for (int c = 0; c < 8; c++) {
        float4 xc = xrow[lane + 64 * c];
        xf[c * 4 + 0] = xc.x;
        xf[c * 4 + 1] = xc.y;
        xf[c * 4 + 2] = xc.z;
        xf[c * 4 + 3] = xc.w;
    }

    float acc[32];
#pragma unroll
    for (int k = 0; k < 32; k++) acc[k] = 0.f;

    int cur = 0;
#pragma unroll
    for (int l = 0; l < DEPTHP1; l++) {
        const float4* wrow = (const float4*)(w_in + (size_t)cur * D_IN);
        float part = 0.f;
#pragma unroll
        for (int c = 0; c < 8; c++) {
            float4 wc = wrow[lane + 64 * c];
            part += wc.x * xf[c * 4 + 0];
            part += wc.y * xf[c * 4 + 1];
            part += wc.z * xf[c * 4 + 2];
            part += wc.w * xf[c * 4 + 3];
        }
        // 64-lane butterfly: every lane ends with the identical full sum.
#pragma unroll
        for (int off = 32; off >= 1; off >>= 1)
            part += __shfl_xor(part, off, 64);
        const float score = part;
        const float g = 0.5f * score * (1.0f + erff(score * 0.70710678118654752f));

        if (TRANSPOSED) {
            // acc += g * w_out_T[cur][:], contiguous row
            const float4* orow = (const float4*)(w_out + (size_t)cur * D_OUT);
#pragma unroll
            for (int c = 0; c < 8; c++) {
                float4 oc = orow[lane + 64 * c];
                acc[c * 4 + 0] += g * oc.x;
                acc[c * 4 + 1] += g * oc.y;
                acc[c * 4 + 2] += g * oc.z;
                acc[c * 4 + 3] += g * oc.w;
            }
        } else {
            // acc += g * w_out[:, cur], stride-N_NODES column gather (slow path)
#pragma unroll
            for (int c = 0; c < 8; c++) {
#pragma unroll
                for (int k = 0; k < 4; k++) {
                    const int j = (lane + 64 * c) * 4 + k;
                    acc[c * 4 + k] += g * w_out[(size_t)j * N_NODES + cur];
                }
            }
        }
        cur = 2 * cur + 1 + (score >= 0.f ? 1 : 0);
    }

    float4* outrow = (float4*)(out + (size_t)token * D_OUT);
#pragma unroll
    for (int c = 0; c < 8; c++) {
        float4 o;
        o.x = acc[c * 4 + 0];
        o.y = acc[c * 4 + 1];
        o.z = acc[c * 4 + 2];
        o.w = acc[c * 4 + 3];
        outrow[lane + 64 * c] = o;
    }
}

extern "C" void kernel_launch(void* const* d_in, const int* in_sizes, int n_in,
                              void* d_out, int out_size, void* d_ws, size_t ws_size,
                              hipStream_t stream) {
    (void)in_sizes; (void)n_in; (void)out_size;
    const float* x     = (const float*)d_in[0];
    const float* w_in  = (const float*)d_in[1];
    const float* w_out = (const float*)d_in[2];
    float* out = (float*)d_out;

    const size_t wt_bytes = (size_t)N_NODES * D_OUT * sizeof(float); // 33.5 MB
    if (ws_size >= wt_bytes) {
        float* w_out_t = (float*)d_ws;
        dim3 tgrid((N_NODES + 31) / 32, D_OUT / 32);
        transpose_wout<<<tgrid, dim3(32, 32), 0, stream>>>(w_out, w_out_t);
        fff_kernel<true><<<N_TOK / 4, 256, 0, stream>>>(x, w_in, w_out_t, out);
    } else {
        fff_kernel<false><<<N_TOK / 4, 256, 0, stream>>>(x, w_in, w_out, out);
    }
}